// Round 7
// baseline (236.300 us; speedup 1.0000x reference)
//
#include <hip/hip_runtime.h>

// Problem: B=2048 batches, N=64 members, D=256, H=16.
// out[b,n] = softmax_n( relu( (N*u[b,n,:] - sum_n u[b,n,:]) * item[b,:] @ W1 + b1 ) @ W2 )
// (b2 dropped: softmax is shift-invariant.)
//
// R6 lesson: structure correct (absmax==R0), but fully-unrolled compute_tile
// let the scheduler hoist all 64 ds_reads -> ~300 VGPR demand -> 128-clamp +
// 95MB scratch -> 93us. The live window must be capped STRUCTURALLY:
// this version software-pipelines the inner loop with two NAMED register
// sets (A/B) + sched_barrier(0) after each FMA group. Step i's FMAs overlap
// step i+1's in-flight ds_reads; nothing can hoist past the barrier.
// Live set ~100 VGPRs < 128 clamp -> no spill.
//
// Everything else as R6 (verified correct):
//  * global_load_lds staging, pre-swizzled global source col, XOR'd read col
//  * counted-vmcnt 2-deep tile pipeline, zero barriers in the loop
//  * item in 4 regs/lane, per-step wave-uniform broadcast via v_readlane
// LDS: W1 16KB + 4 waves x 2 x 8KB = 80KB -> 2 blocks/CU (grid 512 = 2/CU).

static constexpr int NMEM = 64;
static constexpr int DDIM = 256;

__device__ __forceinline__ void fma4(float4& a, float s, const float4& w) {
    a.x = fmaf(s, w.x, a.x); a.y = fmaf(s, w.y, a.y);
    a.z = fmaf(s, w.z, a.z); a.w = fmaf(s, w.w, a.w);
}
__device__ __forceinline__ float rdlane(float v, int srclane) {
    return __int_as_float(__builtin_amdgcn_readlane(__float_as_int(v), srclane));
}

__global__ __launch_bounds__(256, 2)
void attn_group_softmax(const float* __restrict__ u_g,     // [B,64,256]
                        const float* __restrict__ item_g,  // [B,256]
                        const float* __restrict__ W1,      // [256,16]
                        const float* __restrict__ b1,      // [16]
                        const float* __restrict__ W2,      // [16,1]
                        float* __restrict__ out)           // [B,64]
{
    __shared__ float w1s[DDIM * 16];         // 16 KB, shared by all 4 waves
    __shared__ float tiles[4][2][NMEM * 32]; // 4 waves x 2 bufs x 8KB

    const int tid  = threadIdx.x;
    const int w    = tid >> 6;               // wave id 0..3
    const int lane = tid & 63;
    const int b    = blockIdx.x * 4 + w;     // one batch per wave

    // ---- stage W1 (block-wide) + item (4 regs/lane) ----
    {
        const float4* src = (const float4*)W1;
        float4* dst = (float4*)w1s;
        #pragma unroll
        for (int i = 0; i < 4; ++i) dst[tid + 256 * i] = src[tid + 256 * i];
    }
    const float4 it4 = ((const float4*)(item_g + (size_t)b * DDIM))[lane];
    __syncthreads();   // the ONLY barrier (w1s visibility; drains prologue vmem)

    const int q    = lane & 3;               // h-group: h = 4q..4q+3
    const int n0   = lane >> 2;              // 0..15; owns n = n0 + 16k
    const int pk   = n0 & 7;                 // read swizzle key
    const int sco  = (lane & 7) ^ (lane >> 3);   // pre-swizzled global col

    const float4* gstage = (const float4*)u_g + (size_t)b * (NMEM * DDIM / 4)
                         + (lane >> 3) * (DDIM / 4) + sco;
    float* const tb0 = &tiles[w][0][0];
    float* const tb1 = &tiles[w][1][0];
    const float4* w1s4 = (const float4*)w1s;

    // stage tile t (8 async 1KB chunks; LDS dest wave-uniform, linear)
    auto stage = [&](int t, float* lb) {
        const float4* g = gstage + t * 8;
        #pragma unroll
        for (int k = 0; k < 8; ++k)
            __builtin_amdgcn_global_load_lds(
                (const __attribute__((address_space(1))) void*)(g + k * 512),
                (__attribute__((address_space(3))) void*)(lb + k * 256),
                16, 0, 0);
    };

    float4 acc0 = make_float4(0.f, 0.f, 0.f, 0.f);
    float4 acc1 = acc0, acc2 = acc0, acc3 = acc0;

    // A/B named register sets for the software-pipelined inner loop
    float4 uaA, ubA, ucA, udA, w0A, w1A, w2A, w3A;
    float4 uaB, ubB, ucB, udB, w0B, w1B, w2B, w3B;

    #define LOAD_SET(S, lb4, t, d4)                                          \
    {                                                                        \
        const int p_ = (d4) ^ pk;                                            \
        ua##S = (lb4)[(n0     ) * 8 + p_];                                   \
        ub##S = (lb4)[(n0 + 16) * 8 + p_];                                   \
        uc##S = (lb4)[(n0 + 32) * 8 + p_];                                   \
        ud##S = (lb4)[(n0 + 48) * 8 + p_];                                   \
        const int wb_ = ((t) * 32 + (d4) * 4) * 4 + q;                       \
        w0##S = w1s4[wb_];      w1##S = w1s4[wb_ + 4];                       \
        w2##S = w1s4[wb_ + 8];  w3##S = w1s4[wb_ + 12];                      \
    }

    #define FMA_SET(S, t, d4)                                                \
    {                                                                        \
        const int f_ = (t) * 8 + (d4);                                       \
        const float itx = rdlane(it4.x, f_);                                 \
        const float ity = rdlane(it4.y, f_);                                 \
        const float itz = rdlane(it4.z, f_);                                 \
        const float itw = rdlane(it4.w, f_);                                 \
        { const float s0 = ua##S.x*itx, s1 = ua##S.y*ity,                    \
                      s2 = ua##S.z*itz, s3 = ua##S.w*itw;                    \
          fma4(acc0, s0, w0##S); fma4(acc0, s1, w1##S);                      \
          fma4(acc0, s2, w2##S); fma4(acc0, s3, w3##S); }                    \
        { const float s0 = ub##S.x*itx, s1 = ub##S.y*ity,                    \
                      s2 = ub##S.z*itz, s3 = ub##S.w*itw;                    \
          fma4(acc1, s0, w0##S); fma4(acc1, s1, w1##S);                      \
          fma4(acc1, s2, w2##S); fma4(acc1, s3, w3##S); }                    \
        { const float s0 = uc##S.x*itx, s1 = uc##S.y*ity,                    \
                      s2 = uc##S.z*itz, s3 = uc##S.w*itw;                    \
          fma4(acc2, s0, w0##S); fma4(acc2, s1, w1##S);                      \
          fma4(acc2, s2, w2##S); fma4(acc2, s3, w3##S); }                    \
        { const float s0 = ud##S.x*itx, s1 = ud##S.y*ity,                    \
                      s2 = ud##S.z*itz, s3 = ud##S.w*itw;                    \
          fma4(acc3, s0, w0##S); fma4(acc3, s1, w1##S);                      \
          fma4(acc3, s2, w2##S); fma4(acc3, s3, w3##S); }                    \
    }
    #define SB __builtin_amdgcn_sched_barrier(0)

    // compute tile t: 8 d4-steps, A/B pipelined, live window = 2 sets only
    auto compute_tile = [&](int t, const float* lb) {
        const float4* lb4 = (const float4*)lb;
        LOAD_SET(A, lb4, t, 0)
        LOAD_SET(B, lb4, t, 1)
        FMA_SET(A, t, 0)  SB;
        LOAD_SET(A, lb4, t, 2)
        FMA_SET(B, t, 1)  SB;
        LOAD_SET(B, lb4, t, 3)
        FMA_SET(A, t, 2)  SB;
        LOAD_SET(A, lb4, t, 4)
        FMA_SET(B, t, 3)  SB;
        LOAD_SET(B, lb4, t, 5)
        FMA_SET(A, t, 4)  SB;
        LOAD_SET(A, lb4, t, 6)
        FMA_SET(B, t, 5)  SB;
        LOAD_SET(B, lb4, t, 7)
        FMA_SET(A, t, 6)  SB;
        FMA_SET(B, t, 7)  SB;
    };

    // ---- pipelined K-loop: 2 tiles in flight, vmcnt(8) at tile top ----
    stage(0, tb0);
    stage(1, tb1);
    #pragma unroll 1
    for (int t = 0; t < 7; ++t) {
        asm volatile("s_waitcnt vmcnt(8)" ::: "memory");   // tile t landed
        float* lb = (t & 1) ? tb1 : tb0;
        compute_tile(t, lb);
        asm volatile("s_waitcnt lgkmcnt(0)" ::: "memory"); // reads done: WAR-safe
        if (t < 6) stage(t + 2, lb);                       // t+2 has same parity
    }
    asm volatile("s_waitcnt vmcnt(0)" ::: "memory");
    compute_tile(7, tb1);

    #undef LOAD_SET
    #undef FMA_SET
    #undef SB

    // ---- epilogue (registers + shuffles only; identical to R0/R6) ----
    float4 tt;
    tt.x = acc0.x + acc1.x + acc2.x + acc3.x;
    tt.y = acc0.y + acc1.y + acc2.y + acc3.y;
    tt.z = acc0.z + acc1.z + acc2.z + acc3.z;
    tt.w = acc0.w + acc1.w + acc2.w + acc3.w;
    #pragma unroll
    for (int off = 4; off <= 32; off <<= 1) {
        tt.x += __shfl_xor(tt.x, off, 64);
        tt.y += __shfl_xor(tt.y, off, 64);
        tt.z += __shfl_xor(tt.z, off, 64);
        tt.w += __shfl_xor(tt.w, off, 64);
    }

    const float4 b1v = ((const float4*)b1)[q];
    const float4 w2v = ((const float4*)W2)[q];

    auto logit_part = [&](const float4& a) -> float {
        const float zx = fmaxf(fmaf(64.f, a.x, b1v.x - tt.x), 0.f);
        const float zy = fmaxf(fmaf(64.f, a.y, b1v.y - tt.y), 0.f);
        const float zz = fmaxf(fmaf(64.f, a.z, b1v.z - tt.z), 0.f);
        const float zw = fmaxf(fmaf(64.f, a.w, b1v.w - tt.w), 0.f);
        return zx * w2v.x + zy * w2v.y + zz * w2v.z + zw * w2v.w;
    };

    float p0 = logit_part(acc0);
    float p1 = logit_part(acc1);
    float p2 = logit_part(acc2);
    float p3 = logit_part(acc3);
    p0 += __shfl_xor(p0, 1, 64); p0 += __shfl_xor(p0, 2, 64);
    p1 += __shfl_xor(p1, 1, 64); p1 += __shfl_xor(p1, 2, 64);
    p2 += __shfl_xor(p2, 1, 64); p2 += __shfl_xor(p2, 2, 64);
    p3 += __shfl_xor(p3, 1, 64); p3 += __shfl_xor(p3, 2, 64);

    float m = fmaxf(fmaxf(p0, p1), fmaxf(p2, p3));
    #pragma unroll
    for (int off = 4; off <= 32; off <<= 1) m = fmaxf(m, __shfl_xor(m, off, 64));
    const float e0 = __expf(p0 - m);
    const float e1 = __expf(p1 - m);
    const float e2 = __expf(p2 - m);
    const float e3 = __expf(p3 - m);
    float s = e0 + e1 + e2 + e3;
    #pragma unroll
    for (int off = 4; off <= 32; off <<= 1) s += __shfl_xor(s, off, 64);
    const float inv = 1.0f / s;

    if (q == 0) {
        float* ob = out + (size_t)b * NMEM + n0;
        ob[0]  = e0 * inv;
        ob[16] = e1 * inv;
        ob[32] = e2 * inv;
        ob[48] = e3 * inv;
    }
}

extern "C" void kernel_launch(void* const* d_in, const int* in_sizes, int n_in,
                              void* d_out, int out_size, void* d_ws, size_t ws_size,
                              hipStream_t stream) {
    const float* u    = (const float*)d_in[0];  // members_embeds [2048,64,256]
    const float* item = (const float*)d_in[1];  // item_embeds   [2048,256]
    const float* W1   = (const float*)d_in[2];  // [256,16]
    const float* b1   = (const float*)d_in[3];  // [16]
    const float* W2   = (const float*)d_in[4];  // [16,1]
    // d_in[5] = b2: dropped (softmax shift-invariant)
    (void)in_sizes; (void)n_in; (void)out_size; (void)d_ws; (void)ws_size;

    attn_group_softmax<<<512, 256, 0, stream>>>(u, item, W1, b1, W2, (float*)d_out);
}

// Round 8
// 202.962 us; speedup vs baseline: 1.1643x; 1.1643x over previous
//
#include <hip/hip_runtime.h>

// Problem: B=2048 batches, N=64 members, D=256, H=16.
// out[b,n] = softmax_n( relu( (N*u[b,n,:] - sum_n u[b,n,:]) * item[b,:] @ W1 + b1 ) @ W2 )
// (b2 dropped: softmax is shift-invariant.)
//
// R3-R7 lesson: every restructure away from the R0 pattern (no-LDS butterfly,
// global_load_lds + vmcnt pipeline, A/B sched_barrier pipelining) hit a
// compiler-allocator pathology (128-VGPR clamp + 40-100MB scratch, or 56-VGPR
// load serialization). R0/R1/R2 (~63us kernel) is the only structure ever
// measured fast. Its limiter: per-CU DS (~19us) + HBM (~21us) + VALU (~8us)
// run nearly SERIALIZED, because grid 512 = 2 blocks/CU = only 8 waves/CU.
//
// This version: identical R0/R1 wave-level structure, but each batch is split
// across TWO waves (n-halves) -> block = 2 batches, grid = 1024 ->
// 4 blocks/CU = 16 waves/CU (2x TLP). Per-wave state halves (r[4], acc[2]).
// Cross-wave tt/max/sum combine via tiny LDS exchange + 3 epilogue barriers.
// No barriers in the tile loop (wave-private tile, in-order DS per wave --
// verified correct in R1/R2). LDS 37KB/block; launch_bounds(256,4) caps
// VGPR at 128 (demand ~75, no spill).

static constexpr int NMEM  = 64;
static constexpr int DDIM  = 256;
static constexpr int TD    = 32;          // d-tile width
static constexpr int NTILE = DDIM / TD;   // 8
static constexpr int UTS   = 36;          // padded LDS row stride (floats)
static constexpr int UTS4  = UTS / 4;     // 9

__device__ __forceinline__ void fma4(float4& acc, float s, const float4& w) {
    acc.x = fmaf(s, w.x, acc.x);
    acc.y = fmaf(s, w.y, acc.y);
    acc.z = fmaf(s, w.z, acc.z);
    acc.w = fmaf(s, w.w, acc.w);
}

__global__ __launch_bounds__(256, 4)
void attn_group_softmax(const float* __restrict__ u_g,     // [B,64,256]
                        const float* __restrict__ item_g,  // [B,256]
                        const float* __restrict__ W1,      // [256,16]
                        const float* __restrict__ b1,      // [16]
                        const float* __restrict__ W2,      // [16,1]
                        float* __restrict__ out)           // [B,64]
{
    __shared__ float  w1s[DDIM * 16];         // 16 KB, shared by all 4 waves
    __shared__ float  item_s[2][DDIM];        // 2 KB, per batch-slot
    __shared__ float  ut[4][32 * UTS];        // 4 waves x 4.5 KB (32-row tile)
    __shared__ float4 xtt[2][2][4];           // tt exchange: [batch][half][q]
    __shared__ float  xm[2][2], xs[2][2];     // max / sum exchange

    const int tid  = threadIdx.x;
    const int w    = tid >> 6;                // wave id 0..3
    const int lane = tid & 63;
    const int bb   = w >> 1;                  // batch slot in block: 0/1
    const int wh   = w & 1;                   // n-half: rows 32*wh..32*wh+31
    const int b    = blockIdx.x * 2 + bb;     // global batch

    // ---- stage W1 (block-wide, 1024 float4) ----
    {
        const float4* src = (const float4*)W1;
        float4* dst = (float4*)w1s;
        #pragma unroll
        for (int i = 0; i < 4; ++i) dst[tid + 256 * i] = src[tid + 256 * i];
    }
    // ---- stage item (one wave per batch-slot, 64 float4) ----
    if (wh == 0)
        ((float4*)item_s[bb])[lane] =
            ((const float4*)(item_g + (size_t)b * DDIM))[lane];
    __syncthreads();   // w1s + item_s visible to all waves

    const int q    = lane & 3;   // h-group: h = 4q..4q+3
    const int n0   = lane >> 2;  // 0..15; owns local n = n0, n0+16
    const int col4 = lane & 7;   // staging float4 column within tile
    const int row0 = lane >> 3;  // staging row 0..7 (+8i, i<4 -> rows 0..31)

    const float4* ug4  = (const float4*)u_g + (size_t)b * (NMEM * DDIM / 4)
                       + (32 * wh) * (DDIM / 4);      // this wave's n-half
    const float4* it4p = (const float4*)item_s[bb];
    float4*       uts4 = (float4*)ut[w];
    const float4* utf4 = (const float4*)ut[w];
    const float4* w1s4 = (const float4*)w1s;

    float4 acc0 = make_float4(0.f, 0.f, 0.f, 0.f);   // local n = n0
    float4 acc1 = acc0;                               // local n = n0+16

    // prefetch tile 0 (4 x float4 per lane = full 32x32 half-tile per wave)
    float4 r[4];
    #pragma unroll
    for (int i = 0; i < 4; ++i)
        r[i] = ug4[(row0 + 8 * i) * (DDIM / 4) + col4];

    for (int t = 0; t < NTILE; ++t) {
        // write tile t to LDS, folding in item (R0 pattern, wave-private tile)
        const float4 itv = it4p[t * 8 + col4];
        #pragma unroll
        for (int i = 0; i < 4; ++i) {
            float4 v = r[i];
            v.x *= itv.x; v.y *= itv.y; v.z *= itv.z; v.w *= itv.w;
            uts4[(row0 + 8 * i) * UTS4 + col4] = v;
        }
        // prefetch tile t+1 (overlaps compute below)
        if (t + 1 < NTILE) {
            #pragma unroll
            for (int i = 0; i < 4; ++i)
                r[i] = ug4[(row0 + 8 * i) * (DDIM / 4) + (t + 1) * 8 + col4];
        }
        // compute tile t: per 4 d-columns, 2 u-reads + 4 W1-reads + 32 FMA.
        // No barrier: tile is wave-private; DS ops from one wave are in-order,
        // so write->read->overwrite is safe (verified R1/R2).
        #pragma unroll
        for (int d4 = 0; d4 < TD / 4; ++d4) {
            const float4 ua = utf4[(n0     ) * UTS4 + d4];
            const float4 ub = utf4[(n0 + 16) * UTS4 + d4];
            const int dbase = (t * TD + d4 * 4) * 4 + q;
            const float4 w0  = w1s4[dbase];
            const float4 w1r = w1s4[dbase + 4];
            const float4 w2r = w1s4[dbase + 8];
            const float4 w3r = w1s4[dbase + 12];
            fma4(acc0, ua.x, w0); fma4(acc0, ua.y, w1r);
            fma4(acc0, ua.z, w2r); fma4(acc0, ua.w, w3r);
            fma4(acc1, ub.x, w0); fma4(acc1, ub.y, w1r);
            fma4(acc1, ub.z, w2r); fma4(acc1, ub.w, w3r);
        }
    }

    // ---- epilogue ----
    // wave-partial tt[h]: sum over this wave's 32 n (2 local + butterfly over
    // the 16 n0-lanes sharing q: XOR 4,8,16,32)
    float4 tt;
    tt.x = acc0.x + acc1.x;
    tt.y = acc0.y + acc1.y;
    tt.z = acc0.z + acc1.z;
    tt.w = acc0.w + acc1.w;
    #pragma unroll
    for (int off = 4; off <= 32; off <<= 1) {
        tt.x += __shfl_xor(tt.x, off, 64);
        tt.y += __shfl_xor(tt.y, off, 64);
        tt.z += __shfl_xor(tt.z, off, 64);
        tt.w += __shfl_xor(tt.w, off, 64);
    }
    // cross-wave combine (other n-half of this batch)
    if (lane < 4) xtt[bb][wh][lane] = tt;   // lane == q for lane<4
    __syncthreads();
    {
        const float4 o = xtt[bb][wh ^ 1][q];
        tt.x += o.x; tt.y += o.y; tt.z += o.z; tt.w += o.w;
    }

    const float4 b1v = ((const float4*)b1)[q];
    const float4 w2v = ((const float4*)W2)[q];

    auto logit_part = [&](const float4& a) -> float {
        const float zx = fmaxf(fmaf(64.f, a.x, b1v.x - tt.x), 0.f);
        const float zy = fmaxf(fmaf(64.f, a.y, b1v.y - tt.y), 0.f);
        const float zz = fmaxf(fmaf(64.f, a.z, b1v.z - tt.z), 0.f);
        const float zw = fmaxf(fmaf(64.f, a.w, b1v.w - tt.w), 0.f);
        return zx * w2v.x + zy * w2v.y + zz * w2v.z + zw * w2v.w;
    };

    float p0 = logit_part(acc0);   // global n = 32*wh + n0
    float p1 = logit_part(acc1);   // global n = 32*wh + n0 + 16
    p0 += __shfl_xor(p0, 1, 64); p0 += __shfl_xor(p0, 2, 64);
    p1 += __shfl_xor(p1, 1, 64); p1 += __shfl_xor(p1, 2, 64);

    // softmax over 64 n: wave-local over 32 n, then cross-wave via LDS
    float mw = fmaxf(p0, p1);
    #pragma unroll
    for (int off = 4; off <= 32; off <<= 1) mw = fmaxf(mw, __shfl_xor(mw, off, 64));
    if (lane == 0) xm[bb][wh] = mw;
    __syncthreads();
    const float m = fmaxf(mw, xm[bb][wh ^ 1]);

    const float e0 = __expf(p0 - m);
    const float e1 = __expf(p1 - m);
    float sw = e0 + e1;
    #pragma unroll
    for (int off = 4; off <= 32; off <<= 1) sw += __shfl_xor(sw, off, 64);
    if (lane == 0) xs[bb][wh] = sw;
    __syncthreads();
    const float inv = 1.0f / (sw + xs[bb][wh ^ 1]);

    if (q == 0) {
        float* ob = out + (size_t)b * NMEM + 32 * wh + n0;
        ob[0]  = e0 * inv;   // 16 lanes, 64 B contiguous
        ob[16] = e1 * inv;
    }
}

extern "C" void kernel_launch(void* const* d_in, const int* in_sizes, int n_in,
                              void* d_out, int out_size, void* d_ws, size_t ws_size,
                              hipStream_t stream) {
    const float* u    = (const float*)d_in[0];  // members_embeds [2048,64,256]
    const float* item = (const float*)d_in[1];  // item_embeds   [2048,256]
    const float* W1   = (const float*)d_in[2];  // [256,16]
    const float* b1   = (const float*)d_in[3];  // [16]
    const float* W2   = (const float*)d_in[4];  // [16,1]
    // d_in[5] = b2: dropped (softmax shift-invariant)
    (void)in_sizes; (void)n_in; (void)out_size; (void)d_ws; (void)ws_size;

    attn_group_softmax<<<1024, 256, 0, stream>>>(u, item, W1, b1, W2, (float*)d_out);
}